// Round 15
// baseline (1272.488 us; speedup 1.0000x reference)
//
#include <hip/hip_runtime.h>
#include <math.h>

#define DIMN 20
#define DD 21
#define NN 2048
#define MCN 32
#define UNITS 128
#define SIGC 0.2f
#define MUC 0.05f
#define RC 0.05f
#define DELTAC 0.01f

#define TM 32
#define PTOT (NN + MCN*NN + NN)
#define NBLK (PTOT/TM)

// ws layout (floats)
#define OFF_L 0
#define OFF_WT 512
#define OFF_UZGR (OFF_WT + 4*16384)      // 66048 : packed [Uz|Ug|Ur] 21x384 (pad to 8192)
#define OFF_WZGR (OFF_UZGR + 8192)       // 74240 : packed [Wz|Wg|Wr] 128x384
#define OFF_FP1  (OFF_WZGR + 49152)      // 123392
#define OFF_VAL1 (OFF_FP1 + NN*DD)       // 166400
#define OFF_VAL2 (OFF_VAL1 + NN)         // 168448
#define OFF_T12  (OFF_VAL2 + NN)         // 170496
#define OFF_GATES (OFF_T12 + NN)         // 172544 : per-block stash

// per-block stash (floats), per-thread-linear layout; h recovered, not stashed
#define ST_S1 0
#define ST_Z1 4096
#define ST_G1 8192
#define ST_R1 12288
#define ST_Z2 16384
#define ST_G2 20480
#define ST_R2 24576
#define GB_STRIDE 28672     // total stash = (172544 + 2176*28672)*4 B = 250.3 MB

// LDS layouts (floats)
// SG: S0 0 | S2 4096 | Db 8192 | Db2 12288 | xT 16384 | Vb 17056 | tot 17728 (70.9KB -> 2 blk/CU)
//     backward: S0 doubles as Db3 (dhp); s0 recomputed from xT into S2 for layer 1.
// RC: S0 0 | S1 4096 | S2 8192 | Db 12288 | Db2 16384 | Db3 20480 | xT 24576 | Vb 25248
//     tot 25920 (103.7KB -> 1 blk/CU, fallback only)
#define L_TOT_SG 17728
#define L_TOT_RC 25920

#define ELT44(...) _Pragma("unroll") for (int p = 0; p < 4; p++){ _Pragma("unroll") for (int jj = 0; jj < 4; jj++){ __VA_ARGS__; } }

__device__ __forceinline__ int offq(int row, int p0){
    return row*32 + ((p0 + 4*(row&7)) & 31);
}
__device__ __forceinline__ int offs(int row, int p){
    return row*32 + (((p & 28) + 4*(row&7)) & 31) + (p & 3);
}

// fast tanh: 1 - 2/(e^{2x}+1), clamp to +-9, ~6 VALU vs ~25 libm
__device__ __forceinline__ float ftanh(float x){
    float cx = fminf(9.f, fmaxf(-9.f, x));
    float e  = __expf(2.f*cx);
    return fmaf(-2.f, __builtin_amdgcn_rcpf(e + 1.f), 1.f);
}

#define FMA16(acc, s4, w4) \
  acc[0][0]=fmaf(s4.x,w4.x,acc[0][0]); acc[0][1]=fmaf(s4.x,w4.y,acc[0][1]); \
  acc[0][2]=fmaf(s4.x,w4.z,acc[0][2]); acc[0][3]=fmaf(s4.x,w4.w,acc[0][3]); \
  acc[1][0]=fmaf(s4.y,w4.x,acc[1][0]); acc[1][1]=fmaf(s4.y,w4.y,acc[1][1]); \
  acc[1][2]=fmaf(s4.y,w4.z,acc[1][2]); acc[1][3]=fmaf(s4.y,w4.w,acc[1][3]); \
  acc[2][0]=fmaf(s4.z,w4.x,acc[2][0]); acc[2][1]=fmaf(s4.z,w4.y,acc[2][1]); \
  acc[2][2]=fmaf(s4.z,w4.z,acc[2][2]); acc[2][3]=fmaf(s4.z,w4.w,acc[2][3]); \
  acc[3][0]=fmaf(s4.w,w4.x,acc[3][0]); acc[3][1]=fmaf(s4.w,w4.y,acc[3][1]); \
  acc[3][2]=fmaf(s4.w,w4.z,acc[3][2]); acc[3][3]=fmaf(s4.w,w4.w,acc[3][3]);

// direct-global matmul over 128-wide W rows; L2-hot weights; NO barriers.
__device__ __forceinline__ void mm_d(const float* __restrict__ gW, int K,
    const float* __restrict__ vec, float acc[4][4], int jg, int p0)
{
    const float* wp = gW + 4*jg;
    __builtin_amdgcn_s_setprio(1);
    #pragma unroll 8
    for (int k = 0; k < K; k++){
        float4 w4 = *(const float4*)(wp + k*UNITS);
        float4 s4 = *(const float4*)(vec + offq(k, p0));
        FMA16(acc, s4, w4)
    }
    __builtin_amdgcn_s_setprio(0);
}
// fused U(K=21)+W(K=128) single-gate matmul: dual phase then W-only phase
__device__ __forceinline__ void mm_uw_d(const float* __restrict__ gU, const float* __restrict__ gW,
    const float* __restrict__ vecU, const float* __restrict__ vecW,
    float acc[4][4], int jg, int p0)
{
    const float* up = gU + 4*jg;
    const float* wp = gW + 4*jg;
    __builtin_amdgcn_s_setprio(1);
    #pragma unroll 3
    for (int k = 0; k < DD; k++){
        float4 w4 = *(const float4*)(wp + k*UNITS);
        float4 s4 = *(const float4*)(vecW + offq(k, p0));
        float4 u4 = *(const float4*)(up + k*UNITS);
        float4 x4 = *(const float4*)(vecU + offq(k, p0));
        FMA16(acc, s4, w4)
        FMA16(acc, x4, u4)
    }
    #pragma unroll 8
    for (int k = DD; k < UNITS; k++){
        float4 w4 = *(const float4*)(wp + k*UNITS);
        float4 s4 = *(const float4*)(vecW + offq(k, p0));
        FMA16(acc, s4, w4)
    }
    __builtin_amdgcn_s_setprio(0);
}
// fused triple: z+g streams accumulate into accAB, h stream into accC.
__device__ __forceinline__ void mm3w_d(const float* __restrict__ gWa, const float* __restrict__ gWb,
    const float* __restrict__ gWc, int K,
    const float* __restrict__ vecA, const float* __restrict__ vecB, const float* __restrict__ vecC,
    float accAB[4][4], float accC[4][4], int jg, int p0)
{
    const float* wpa = gWa + 4*jg;
    const float* wpb = gWb + 4*jg;
    const float* wpc = gWc + 4*jg;
    __builtin_amdgcn_s_setprio(1);
    #pragma unroll 2
    for (int k = 0; k < K; k++){
        float4 wa = *(const float4*)(wpa + k*UNITS);
        float4 sa = *(const float4*)(vecA + offq(k, p0));
        float4 wb = *(const float4*)(wpb + k*UNITS);
        float4 sb = *(const float4*)(vecB + offq(k, p0));
        float4 wc = *(const float4*)(wpc + k*UNITS);
        float4 sc = *(const float4*)(vecC + offq(k, p0));
        FMA16(accAB, sa, wa)
        FMA16(accAB, sb, wb)
        FMA16(accC,  sc, wc)
    }
    __builtin_amdgcn_s_setprio(0);
}
// fused z,g,r gates over 384-packed rows: dual U(21)+W(128) phase, then W-only
__device__ __forceinline__ void mm3_uw_d(const float* __restrict__ gU, const float* __restrict__ gW,
    const float* __restrict__ vecU, const float* __restrict__ vecW,
    float a0[4][4], float a1[4][4], float a2[4][4], int jg, int p0)
{
    const float* up = gU + 4*jg;
    const float* wp = gW + 4*jg;
    __builtin_amdgcn_s_setprio(1);
    for (int k = 0; k < DD; k++){
        const float* wr_ = wp + k*384;
        const float* ur_ = up + k*384;
        float4 s4 = *(const float4*)(vecW + offq(k, p0));
        float4 x4 = *(const float4*)(vecU + offq(k, p0));
        float4 w0 = *(const float4*)(wr_);
        float4 w1v = *(const float4*)(wr_ + 128);
        float4 w2 = *(const float4*)(wr_ + 256);
        float4 u0 = *(const float4*)(ur_);
        float4 u1 = *(const float4*)(ur_ + 128);
        float4 u2 = *(const float4*)(ur_ + 256);
        FMA16(a0, s4, w0) FMA16(a1, s4, w1v) FMA16(a2, s4, w2)
        FMA16(a0, x4, u0) FMA16(a1, x4, u1) FMA16(a2, x4, u2)
    }
    #pragma unroll 4
    for (int k = DD; k < UNITS; k++){
        const float* r = wp + k*384;
        float4 s4 = *(const float4*)(vecW + offq(k, p0));
        float4 w0 = *(const float4*)(r);
        float4 w1v = *(const float4*)(r + 128);
        float4 w2 = *(const float4*)(r + 256);
        FMA16(a0, s4, w0) FMA16(a1, s4, w1v) FMA16(a2, s4, w2)
    }
    __builtin_amdgcn_s_setprio(0);
}

__device__ __forceinline__ void write_own(float* buf, const float v[4][4], int j0, int p0){
    #pragma unroll
    for (int jj = 0; jj < 4; jj++){
        int j = j0 + jj;
        float4 q = make_float4(v[0][jj], v[1][jj], v[2][jj], v[3][jj]);
        *(float4*)(buf + offq(j, p0)) = q;
    }
}
__device__ __forceinline__ void read_own(const float* buf, float v[4][4], int j0, int p0){
    #pragma unroll
    for (int jj = 0; jj < 4; jj++){
        int j = j0 + jj;
        float4 q = *(const float4*)(buf + offq(j, p0));
        v[0][jj]=q.x; v[1][jj]=q.y; v[2][jj]=q.z; v[3][jj]=q.w;
    }
}
// per-thread-linear global stash (coalesced; only same thread reads back)
__device__ __forceinline__ void stash_w(float* buf, const float v[4][4], int t){
    #pragma unroll
    for (int jj = 0; jj < 4; jj++)
        *(float4*)(buf + (jj*256 + t)*4) = make_float4(v[0][jj], v[1][jj], v[2][jj], v[3][jj]);
}
__device__ __forceinline__ void stash_r(const float* buf, float v[4][4], int t){
    #pragma unroll
    for (int jj = 0; jj < 4; jj++){
        float4 q = *(const float4*)(buf + (jj*256 + t)*4);
        v[0][jj]=q.x; v[1][jj]=q.y; v[2][jj]=q.z; v[3][jj]=q.w;
    }
}

// out = tanh(bias + x@U + vec@W)  (h gate); fused U+W streams
__device__ __forceinline__ void gate_f(const float* __restrict__ U, const float* __restrict__ W,
    const float* __restrict__ bias, const float* __restrict__ xT, const float* __restrict__ Sin,
    float out[4][4], int jg, int p0, int j0)
{
    float acc[4][4];
    float4 b = *(const float4*)(bias + j0);
    #pragma unroll
    for (int p = 0; p < 4; p++){ acc[p][0]=b.x; acc[p][1]=b.y; acc[p][2]=b.z; acc[p][3]=b.w; }
    mm_uw_d(U, W, xT, Sin, acc, jg, p0);
    #pragma unroll
    for (int p = 0; p < 4; p++)
        #pragma unroll
        for (int jj = 0; jj < 4; jj++) out[p][jj] = ftanh(acc[p][jj]);
}

// fused z,g,r gates; fused U+W streams; NO internal barriers
__device__ __forceinline__ void gate3_f(const float* __restrict__ Uzgr, const float* __restrict__ Wzgr,
    const float* __restrict__ bz, const float* __restrict__ bg, const float* __restrict__ br,
    const float* __restrict__ xT, const float* __restrict__ Sin,
    float zt[4][4], float gt[4][4], float rt[4][4],
    int jg, int p0, int j0)
{
    float4 b0 = *(const float4*)(bz + j0);
    float4 b1 = *(const float4*)(bg + j0);
    float4 b2 = *(const float4*)(br + j0);
    #pragma unroll
    for (int p = 0; p < 4; p++){
        zt[p][0]=b0.x; zt[p][1]=b0.y; zt[p][2]=b0.z; zt[p][3]=b0.w;
        gt[p][0]=b1.x; gt[p][1]=b1.y; gt[p][2]=b1.z; gt[p][3]=b1.w;
        rt[p][0]=b2.x; rt[p][1]=b2.y; rt[p][2]=b2.z; rt[p][3]=b2.w;
    }
    mm3_uw_d(Uzgr, Wzgr, xT, Sin, zt, gt, rt, jg, p0);
    ELT44(zt[p][jj]=ftanh(zt[p][jj]); gt[p][jj]=ftanh(gt[p][jj]); rt[p][jj]=ftanh(rt[p][jj]))
}

// closed-form Cholesky of DELTA*((1-RHO)I + RHO*J): equicorrelated structure.
__global__ void chol_kernel(float* __restrict__ Lout)
{
    if (threadIdx.x == 0 && blockIdx.x == 0) {
        const double beta = 0.01 * 0.5;          // off-diagonal
        const double diag = 0.01;                // alpha + beta
        double c[DIMN], d[DIMN];
        double S = 0.0;
        for (int j = 0; j < DIMN; j++){
            double dj = sqrt(diag - S);
            double cj = (beta - S) / dj;
            d[j] = dj; c[j] = cj;
            S += cj*cj;
        }
        for (int i = 0; i < DIMN; i++)
            for (int j = 0; j < DIMN; j++)
                Lout[i*DIMN + j] = (j < i) ? (float)c[j] : (j == i) ? (float)d[i] : 0.0f;
    }
}

__global__ void transpose_k(const float* __restrict__ wz, const float* __restrict__ wg,
                            const float* __restrict__ wr, const float* __restrict__ wh,
                            float* __restrict__ WT)
{
    int idx = blockIdx.x*256 + threadIdx.x;           // 0..65535
    int q = idx >> 14, r2 = idx & 16383, k = r2 >> 7, j = r2 & 127;
    const float* src = (q==0)? wz : (q==1)? wg : (q==2)? wr : wh;
    WT[(q<<14) + j*UNITS + k] = src[k*UNITS + j];
}

// pack [Uz|Ug|Ur] 21x384 and [Wz|Wg|Wr] 128x384
__global__ void pack_zgr(const float* __restrict__ uz, const float* __restrict__ ug,
                         const float* __restrict__ ur,
                         const float* __restrict__ wz, const float* __restrict__ wg,
                         const float* __restrict__ wr,
                         float* __restrict__ Uzgr, float* __restrict__ Wzgr)
{
    int idx = blockIdx.x*256 + threadIdx.x;
    if (idx < 128*384){
        int k = idx/384, c = idx - k*384, g = c >> 7, j = c & 127;
        const float* s = (g==0)? wz : (g==1)? wg : wr;
        Wzgr[idx] = s[k*UNITS + j];
        return;
    }
    int i2 = idx - 128*384;
    if (i2 < 21*384){
        int k = i2/384, c = i2 - k*384, g = c >> 7, j = c & 127;
        const float* s = (g==0)? uz : (g==1)? ug : ur;
        Uzgr[i2] = s[k*UNITS + j];
    }
}

#define DGM_PARAMS \
    const float* __restrict__ inputs, const float* __restrict__ eps, \
    const float* __restrict__ w1, const float* __restrict__ b1, \
    const float* __restrict__ uz, const float* __restrict__ bz, \
    const float* __restrict__ ug, const float* __restrict__ bg, \
    const float* __restrict__ ur, const float* __restrict__ br, \
    const float* __restrict__ uh, const float* __restrict__ wh, const float* __restrict__ bh, \
    const float* __restrict__ wv, const float* __restrict__ bv, \
    const float* __restrict__ Lm, const float* __restrict__ WT, \
    const float* __restrict__ Uzgr, const float* __restrict__ Wzgr, \
    float* __restrict__ gws, \
    float* __restrict__ fp1, float* __restrict__ val1, float* __restrict__ val2, \
    float* __restrict__ t12acc

#define DGM_ARGS inputs, eps, w1, b1, uz, bz, ug, bg, ur, br, uh, wh, bh, wv, bv, \
    Lm, WT, Uzgr, Wzgr, gws, fp1, val1, val2, t12acc

template<int SG>
__device__ __forceinline__ void dgm_body(float* lds, DGM_PARAMS)
{
    float* S0  = lds;
    float* S1  = SG ? lds : lds + 4096;               // RC only
    float* S2  = lds + (SG ? 4096 : 8192);
    float* Db  = lds + (SG ? 8192 : 12288);
    float* Db2 = lds + (SG ? 12288 : 16384);
    float* Db3 = SG ? lds : lds + 20480;              // SG: aliases S0 (clobbered in bwd)
    float* xT  = lds + (SG ? 16384 : 24576);
    float* Vb  = lds + (SG ? 17056 : 25248);

    const int t  = threadIdx.x;
    const int jg = t & 31;
    const int pg = t >> 5;
    const int p0 = pg * 4;
    const int j0 = jg * 4;
    const int P0 = blockIdx.x * TM;
    const int type = (P0 < NN) ? 0 : (P0 < NN + MCN*NN) ? 1 : 2;
    int base_n = 0, mrow = 0;
    if (type == 1){ int q = P0 - NN; mrow = q >> 11; base_n = q & (NN-1); }

    float* gb = gws + (size_t)blockIdx.x * GB_STRIDE;

    // ---- build x tile (and violation V for type 1) ----
    {
        int p = t & 31, kq = t >> 5;
        for (int ki = 0; ki < 3; ki++){
            int k = kq + 8*ki;
            if (k > DIMN) break;
            float xv;
            if (type == 0){
                xv = inputs[(P0 + p)*DD + k];
            } else if (type == 2){
                xv = inputs[(NN + (P0 - NN - MCN*NN) + p)*DD + k];
            } else {
                int n = base_n + p;
                float x1v = inputs[n*DD + k];
                if (k == DIMN) xv = x1v;
                else {
                    const float* ep = eps + (size_t)(mrow*NN + n)*DIMN;
                    float a = x1v;
                    for (int d = 0; d < DIMN; d++) a = fmaf(ep[d], Lm[k*DIMN + d], a);
                    float viol = a * (SIGC * x1v);
                    Vb[offs(k, p)] = viol;
                    xv = x1v + viol;
                }
            }
            xT[offs(k, p)] = xv;
        }
    }
    __syncthreads();

    // ---- forward ----
    float s_own[4][4];
    {
        float acc[4][4];
        float4 b = *(const float4*)(b1 + j0);
        #pragma unroll
        for (int p = 0; p < 4; p++){ acc[p][0]=b.x; acc[p][1]=b.y; acc[p][2]=b.z; acc[p][3]=b.w; }
        mm_d(w1, DD, xT, acc, jg, p0);
        ELT44(s_own[p][jj] = ftanh(acc[p][jj]))
        write_own(S0, s_own, j0, p0);
        __syncthreads();
    }

    float zt[4][4], gt[4][4], rt[4][4], ht[4][4];

#define GATES(SIN, SMUL) \
    gate3_f(Uzgr, Wzgr, bz, bg, br, xT, SIN, zt, gt, rt, jg, p0, j0); \
    __syncthreads(); \
    { float tt[4][4]; ELT44(tt[p][jj] = SMUL[p][jj]*rt[p][jj]) write_own(Db, tt, j0, p0); } \
    __syncthreads(); \
    gate_f(uh, wh, bh, xT, Db, ht, jg, p0, j0);

#define FWD_LAYER(SIN) \
    GATES(SIN, s_own) \
    ELT44(s_own[p][jj] = (1.f - gt[p][jj])*ht[p][jj] + zt[p][jj]*s_own[p][jj])

    FWD_LAYER(S0)                      // layer 1
    if (SG){ if (type != 2){
        stash_w(gb + ST_S1, s_own, t);
        stash_w(gb + ST_Z1, zt, t); stash_w(gb + ST_G1, gt, t); stash_w(gb + ST_R1, rt, t);
    } }
    else   { write_own(S1, s_own, j0, p0); }
    __syncthreads();                   // layer-1 gate_f's Db readers done
    write_own(Db, s_own, j0, p0);      // Sin for layer 2
    __syncthreads();

    FWD_LAYER(Db)                      // layer 2
    if (SG && type != 2){
        stash_w(gb + ST_Z2, zt, t); stash_w(gb + ST_G2, gt, t); stash_w(gb + ST_R2, rt, t);
    }
    write_own(S2, s_own, j0, p0);      // s2 in LDS for backward
    __syncthreads();

    FWD_LAYER(S2)                      // layer 3 -- zt/gt/rt/ht stay live into backward

    // ---- value head ----
    {
        float4 wv4 = *(const float4*)(wv + j0);
        float vs[4];
        #pragma unroll
        for (int p = 0; p < 4; p++)
            vs[p] = s_own[p][0]*wv4.x + s_own[p][1]*wv4.y + s_own[p][2]*wv4.z + s_own[p][3]*wv4.w;
        __syncthreads();   // layer-3 gate_f's Db readers done
        *(float4*)(Db + jg*32 + p0) = make_float4(vs[0], vs[1], vs[2], vs[3]);
        __syncthreads();
        if (t < TM){
            float v = bv[0];
            for (int j2 = 0; j2 < 32; j2++) v += Db[j2*32 + t];
            if (type == 0) val1[P0 + t] = v;
            else if (type == 2) val2[P0 + t - NN - MCN*NN] = v;
        }
        __syncthreads();
    }
    if (type == 2) return;

    // ---- backward ----
    float ds[4][4];
    {
        float4 wv4 = *(const float4*)(wv + j0);
        #pragma unroll
        for (int p = 0; p < 4; p++){ ds[p][0]=wv4.x; ds[p][1]=wv4.y; ds[p][2]=wv4.z; ds[p][3]=wv4.w; }
    }
    float proj[4] = {0.f, 0.f, 0.f, 0.f};
    float dxp[3] = {0.f, 0.f, 0.f};
    const int pi = t >> 3, il = t & 7;

    const float* WTz = WT;
    const float* WTg = WT + 16384;
    const float* WTr = WT + 2*16384;
    const float* WTh = WT + 3*16384;

#define DX_DOT(UMAT, BUF) \
    { _Pragma("unroll") for (int ii = 0; ii < 3; ii++){ \
        int i = il + 8*ii; \
        if (i < DD){ \
            const float* Urow = UMAT + i*UNITS; \
            float a = 0.f; \
            for (int j2 = 0; j2 < UNITS; j2++) a = fmaf(BUF[offs(j2, pi)], Urow[j2], a); \
            dxp[ii] += a; \
        } } }

// K=20 direct-global U pass; reads only own Vb/SEL; no barriers
#define PROJ_D(UMAT, SEL) \
    { float uv[4][4]; \
      ELT44(uv[p][jj] = 0.f) \
      mm_d(UMAT, DIMN, Vb, uv, jg, p0); \
      ELT44(proj[p] += uv[p][jj]*SEL[p][jj]) }

// fused 3-matrix K=20 projection; SELs re-read from LDS (identical bits, frees regs)
#define PROJ3_D(U0m, B0, U1m, B1, U2m, B2) \
    { float uv0[4][4], uv1[4][4], uv2[4][4]; \
      ELT44(uv0[p][jj]=0.f; uv1[p][jj]=0.f; uv2[p][jj]=0.f) \
      const float* q0_ = U0m + 4*jg; \
      const float* q1_ = U1m + 4*jg; \
      const float* q2_ = U2m + 4*jg; \
      __builtin_amdgcn_s_setprio(1); \
      _Pragma("unroll 2") \
      for (int k = 0; k < DIMN; k++){ \
          float4 s4 = *(const float4*)(Vb + offq(k, p0)); \
          float4 w0 = *(const float4*)(q0_ + k*UNITS); \
          float4 w1v = *(const float4*)(q1_ + k*UNITS); \
          float4 w2 = *(const float4*)(q2_ + k*UNITS); \
          FMA16(uv0, s4, w0) FMA16(uv1, s4, w1v) FMA16(uv2, s4, w2) \
      } \
      __builtin_amdgcn_s_setprio(0); \
      { float sel[4][4]; \
        read_own(B0, sel, j0, p0); ELT44(proj[p] += uv0[p][jj]*sel[p][jj]) \
        read_own(B1, sel, j0, p0); ELT44(proj[p] += uv1[p][jj]*sel[p][jj]) \
        read_own(B2, sel, j0, p0); ELT44(proj[p] += uv2[p][jj]*sel[p][jj]) } }

// Backward layer: fused z+g+h pass (dzp->Db, dgp->Db2, dhp->Db3, one sync
// pair, 3-stream fused WTz/WTg/WTh matmul: dsn<-z,g; dsr<-h), then r pass.
// MODE 0: sl=S2(LDS), gates live in regs (layer 3)
// MODE 1: recompute gates from SLP (RC fallback)
// MODE 2: sl=stash S1, z/g/r stash, h=(S2_lds - z*sl)/(1-g)   (SG layer 2)
// MODE 3: sl=SLP(LDS, recomputed s0 in S2), z/g/r stash, h=(stash S1 - z*sl)/(1-g)
#define BWD_LAYER(SLP, MODE, GZ, GG, GR) \
    { \
    float dsn[4][4], dsr[4][4]; \
    if (MODE == 1){ \
        float slg[4][4]; read_own(SLP, slg, j0, p0); \
        GATES(SLP, slg) \
    } \
    { /* fused z+g+h pass */ \
        float sl[4][4], zv[4][4], gv[4][4], hv[4][4]; \
        if (MODE == 2){ stash_r(gb + ST_S1, sl, t); stash_r(gb + GZ, zv, t); stash_r(gb + GG, gv, t); } \
        else if (MODE == 3){ read_own(SLP, sl, j0, p0); stash_r(gb + GZ, zv, t); stash_r(gb + GG, gv, t); } \
        else if (MODE == 0){ read_own(S2, sl, j0, p0); ELT44(zv[p][jj]=zt[p][jj]; gv[p][jj]=gt[p][jj]; hv[p][jj]=ht[p][jj]) } \
        else { read_own(SLP, sl, j0, p0); ELT44(zv[p][jj]=zt[p][jj]; gv[p][jj]=gt[p][jj]; hv[p][jj]=ht[p][jj]) } \
        if (MODE == 2 || MODE == 3){ \
            float sn[4][4]; \
            if (MODE == 2){ read_own(S2, sn, j0, p0); } \
            else { stash_r(gb + ST_S1, sn, t); } \
            ELT44(hv[p][jj] = (sn[p][jj] - zv[p][jj]*sl[p][jj]) / (1.f - gv[p][jj])) \
        } \
        float dzp[4][4], dgp[4][4], dhp[4][4]; \
        ELT44(float d=ds[p][jj]; float zz=zv[p][jj]; \
            dzp[p][jj] = d*sl[p][jj]*(1.f - zz*zz); dsn[p][jj] = d*zz) \
        ELT44(float d=ds[p][jj]; float gg=gv[p][jj]; float hh=hv[p][jj]; \
            dgp[p][jj] = -d*hh*(1.f - gg*gg); \
            dhp[p][jj] = d*(1.f - gg)*(1.f - hh*hh)) \
        __syncthreads(); \
        write_own(Db,  dzp, j0, p0); \
        write_own(Db2, dgp, j0, p0); \
        write_own(Db3, dhp, j0, p0); \
        __syncthreads(); \
        if (type == 1){ PROJ3_D(uz, Db, ug, Db2, uh, Db3) } \
        else { DX_DOT(uz, Db) DX_DOT(ug, Db2) DX_DOT(uh, Db3) } \
        ELT44(dsr[p][jj] = 0.f) \
        mm3w_d(WTz, WTg, WTh, UNITS, Db, Db2, Db3, dsn, dsr, jg, p0); \
    } \
    { /* r pass */ \
        float rv[4][4], sl2[4][4], drp[4][4]; \
        if (MODE == 2){ stash_r(gb + GR, rv, t); stash_r(gb + ST_S1, sl2, t); } \
        else if (MODE == 3){ stash_r(gb + GR, rv, t); read_own(SLP, sl2, j0, p0); } \
        else if (MODE == 0){ ELT44(rv[p][jj] = rt[p][jj]) read_own(S2, sl2, j0, p0); } \
        else { ELT44(rv[p][jj] = rt[p][jj]) read_own(SLP, sl2, j0, p0); } \
        ELT44(float dr=dsr[p][jj]; float rr=rv[p][jj]; \
            drp[p][jj] = dr*sl2[p][jj]*(1.f - rr*rr); dsn[p][jj] += dr*rr) \
        __syncthreads(); \
        write_own(Db, drp, j0, p0); \
        __syncthreads(); \
        if (type == 1){ PROJ_D(ur, drp) } else { DX_DOT(ur, Db) } \
    } \
    mm_d(WTr, UNITS, Db, dsn, jg, p0); \
    ELT44(ds[p][jj] = dsn[p][jj]) \
    }

    BWD_LAYER(S2, 0, ST_Z2, ST_G2, ST_R2)                  // layer 3: gates live
    BWD_LAYER(S1, (SG ? 2 : 1), ST_Z2, ST_G2, ST_R2)       // layer 2
    if (SG){
        // recompute s0 = ftanh(b1 + x@w1) into S2 (dead after layer-2 backward);
        // bit-identical to the forward value (same ops, same order).
        float acc[4][4];
        float4 b = *(const float4*)(b1 + j0);
        #pragma unroll
        for (int p = 0; p < 4; p++){ acc[p][0]=b.x; acc[p][1]=b.y; acc[p][2]=b.z; acc[p][3]=b.w; }
        mm_d(w1, DD, xT, acc, jg, p0);
        float s0r[4][4];
        ELT44(s0r[p][jj] = ftanh(acc[p][jj]))
        __syncthreads();
        write_own(S2, s0r, j0, p0);
        __syncthreads();
        BWD_LAYER(S2, 3, ST_Z1, ST_G1, ST_R1)              // layer 1 (stash; sl from S2)
    } else {
        BWD_LAYER(S0, 1, ST_Z1, ST_G1, ST_R1)              // layer 1 (recompute)
    }

    // first-layer backward + epilogue
    {
        float s0l[4][4];
        read_own((SG ? S2 : S0), s0l, j0, p0);
        float v0[4][4];
        ELT44(v0[p][jj] = ds[p][jj]*(1.f - s0l[p][jj]*s0l[p][jj]))

        if (type == 1){
            PROJ_D(w1, v0)
            __syncthreads();   // last mm_d's Db readers done
            *(float4*)(Db + jg*32 + p0) = make_float4(proj[0], proj[1], proj[2], proj[3]);
            __syncthreads();
            if (t < TM){
                float s = 0.f;
                for (int j2 = 0; j2 < 32; j2++) s += Db[j2*32 + t];
                atomicAdd(t12acc + base_n + t, s);
            }
        } else {
            __syncthreads();   // last mm_d's Db readers done
            write_own(Db, v0, j0, p0);
            __syncthreads();
            DX_DOT(w1, Db)
            #pragma unroll
            for (int ii = 0; ii < 3; ii++){
                int i = il + 8*ii;
                if (i < DD) fp1[(P0 + pi)*DD + i] = dxp[ii];
            }
        }
    }
}

__global__ __launch_bounds__(256) __attribute__((amdgpu_waves_per_eu(2,2))) void dgm_sg(DGM_PARAMS){
    __shared__ float lds[L_TOT_SG];
    dgm_body<1>(lds, DGM_ARGS);
}
__global__ __launch_bounds__(256) __attribute__((amdgpu_waves_per_eu(2,2))) void dgm_rc(DGM_PARAMS){
    __shared__ float lds[L_TOT_RC];
    dgm_body<0>(lds, DGM_ARGS);
}

__global__ void finalize_k(const float* __restrict__ inputs, const float* __restrict__ eps,
    const float* __restrict__ Lm, const float* __restrict__ fp1, const float* __restrict__ val1,
    const float* __restrict__ val2, const float* __restrict__ t12acc, float* __restrict__ out)
{
    int n = blockIdx.x*256 + threadIdx.x;
    if (n >= NN) return;
    float fp[DD];
    #pragma unroll
    for (int k = 0; k < DD; k++) fp[k] = fp1[n*DD + k];
    float t11 = fp[DIMN];
    #pragma unroll
    for (int k = 0; k < DIMN; k++) t11 = fmaf(MUC*inputs[n*DD + k], fp[k], t11);
    float esum[DIMN];
    #pragma unroll
    for (int d = 0; d < DIMN; d++){
        float a = 0.f;
        for (int m = 0; m < MCN; m++) a += eps[(size_t)(m*NN + n)*DIMN + d];
        esum[d] = a;
    }
    float t12b = 0.f;
    #pragma unroll
    for (int k = 0; k < DIMN; k++){
        float loc = inputs[n*DD + k];
        float ssum = (float)MCN * loc;
        #pragma unroll
        for (int d = 0; d < DIMN; d++) ssum = fmaf(esum[d], Lm[k*DIMN + d], ssum);
        float vsum = ssum * (SIGC*loc);
        t12b = fmaf(fp[k], vsum, t12b);
    }
    float term12 = (t12acc[n] - t12b) * (1.0f/(DELTAC*(float)MCN));
    out[n] = t11 + 0.5f*term12 - RC*val1[n];

    float prod = 1.f;
    #pragma unroll
    for (int k = 0; k < DIMN; k++) prod *= inputs[(NN + n)*DD + k];
    float payoff = powf(prod, 1.0f/(float)DIMN);
    if (!(payoff > 0.f)) payoff = 0.f;
    out[NN + n] = val2[n] - payoff;
}

extern "C" void kernel_launch(void* const* d_in, const int* in_sizes, int n_in,
                              void* d_out, int out_size, void* d_ws, size_t ws_size,
                              hipStream_t stream)
{
    const float* inputs = (const float*)d_in[0];
    const float* eps    = (const float*)d_in[1];
    const float* w1     = (const float*)d_in[2];
    const float* b1     = (const float*)d_in[3];
    const float* uz     = (const float*)d_in[4];
    const float* wz     = (const float*)d_in[5];
    const float* bz     = (const float*)d_in[6];
    const float* ug     = (const float*)d_in[7];
    const float* wg     = (const float*)d_in[8];
    const float* bg     = (const float*)d_in[9];
    const float* urr    = (const float*)d_in[10];
    const float* wr     = (const float*)d_in[11];
    const float* br     = (const float*)d_in[12];
    const float* uh     = (const float*)d_in[13];
    const float* wh     = (const float*)d_in[14];
    const float* bh     = (const float*)d_in[15];
    const float* wv     = (const float*)d_in[16];
    const float* bv     = (const float*)d_in[17];

    float* ws    = (float*)d_ws;
    float* Lm    = ws + OFF_L;
    float* WT    = ws + OFF_WT;
    float* Uzgr  = ws + OFF_UZGR;
    float* Wzgr  = ws + OFF_WZGR;
    float* fp1   = ws + OFF_FP1;
    float* val1  = ws + OFF_VAL1;
    float* val2  = ws + OFF_VAL2;
    float* t12   = ws + OFF_T12;
    float* gates = ws + OFF_GATES;
    float* out   = (float*)d_out;

    hipMemsetAsync(t12, 0, NN*sizeof(float), stream);
    hipLaunchKernelGGL(chol_kernel, dim3(1), dim3(64), 0, stream, Lm);
    hipLaunchKernelGGL(transpose_k, dim3(256), dim3(256), 0, stream, wz, wg, wr, wh, WT);
    hipLaunchKernelGGL(pack_zgr, dim3(224), dim3(256), 0, stream, uz, ug, urr, wz, wg, wr, Uzgr, Wzgr);

    size_t need_bytes = ((size_t)OFF_GATES + (size_t)NBLK * (size_t)GB_STRIDE) * sizeof(float);
    if (ws_size >= need_bytes){
        hipLaunchKernelGGL(dgm_sg, dim3(NBLK), dim3(256), 0, stream,
            inputs, eps, w1, b1, uz, bz, ug, bg, urr, br, uh, wh, bh, wv, bv,
            Lm, WT, Uzgr, Wzgr, gates, fp1, val1, val2, t12);
    } else {
        hipLaunchKernelGGL(dgm_rc, dim3(NBLK), dim3(256), 0, stream,
            inputs, eps, w1, b1, uz, bz, ug, bg, urr, br, uh, wh, bh, wv, bv,
            Lm, WT, Uzgr, Wzgr, gates, fp1, val1, val2, t12);
    }
    hipLaunchKernelGGL(finalize_k, dim3(8), dim3(256), 0, stream,
        inputs, eps, Lm, fp1, val1, val2, t12, out);
}